// Round 9
// baseline (7131.231 us; speedup 1.0000x reference)
//
#include <hip/hip_runtime.h>
#include <stdint.h>

typedef unsigned short u16;
typedef unsigned int u32;

#define DEV static __device__ __forceinline__

DEV float bf2f(u16 v){ return __uint_as_float(((u32)v)<<16); }
DEV u16 f2bf(float f){
  u32 u = __float_as_uint(f);
  u32 r = (u + 0x7FFFu + ((u>>16)&1u)) >> 16;
  return (u16)r;
}
// dtype-dispatched input load: f==1 -> fp32 array, f==0 -> bf16 array
DEV float ldx(const void* p, long i, int f){
  return f ? ((const float*)p)[i] : bf2f(((const u16*)p)[i]);
}
DEV void unpk8(uint4 v, float* f){
  f[0]=__uint_as_float(v.x<<16); f[1]=__uint_as_float(v.x&0xFFFF0000u);
  f[2]=__uint_as_float(v.y<<16); f[3]=__uint_as_float(v.y&0xFFFF0000u);
  f[4]=__uint_as_float(v.z<<16); f[5]=__uint_as_float(v.z&0xFFFF0000u);
  f[6]=__uint_as_float(v.w<<16); f[7]=__uint_as_float(v.w&0xFFFF0000u);
}
DEV void unpk4(uint2 v, float* f){
  f[0]=__uint_as_float(v.x<<16); f[1]=__uint_as_float(v.x&0xFFFF0000u);
  f[2]=__uint_as_float(v.y<<16); f[3]=__uint_as_float(v.y&0xFFFF0000u);
}
DEV int iabs(int a){ return a<0? -a : a; }

// ======================= dtype probe =======================
// bf16 N(0,1)-scale data: u16 exponent field never >= 0xC0 (|v|>=2^65).
// fp32 data viewed as u16: half the u16s are mantissa bits (uniform) ->
// ~25% of those have exponent >= 0xC0 (~12.5% overall). Threshold 1%.
__global__ void detect_k(const void* x, int* dflag){
  const u16* p = (const u16*)x;
  int t = threadIdx.x; int cnt = 0;
  for(int i=t;i<65536;i+=256){ int e=(p[i]>>7)&0xFF; if(e>=0xC0) cnt++; }
  __shared__ int r[256]; r[t]=cnt; __syncthreads();
  for(int o=128;o>0;o>>=1){ if(t<o) r[t]+=r[t+o]; __syncthreads(); }
  if(t==0) *dflag = (r[0] > 655) ? 1 : 0;
}

// dtype-aware out sanitizer: NaN/inf -> 4096 (diagnostic tri-state)
__global__ __launch_bounds__(256) void sanitize_k(void* o, long n, const int* df){
  int f = *df;
  long i = (long)blockIdx.x*256 + threadIdx.x;
  long st = (long)gridDim.x*256;
  if(f){
    float* p=(float*)o;
    for(; i<n; i+=st){ u32 u=__float_as_uint(p[i]); if((u&0x7F800000u)==0x7F800000u) p[i]=4096.f; }
  } else {
    u16* p=(u16*)o;
    u16 c = f2bf(4096.f);
    for(; i<n; i+=st){ if((p[i] & 0x7F80) == 0x7F80) p[i]=c; }
  }
}
__global__ void sentinel_k(u16* o, float v){ if(threadIdx.x==0) o[0] = f2bf(v); }

// ======================= pipeline =======================
// Direct 3x3 stride-2 pad-1 conv, Cin=256 -> Cout=512 (proj path). All
// operands are harness inputs -> dtype-dispatched loads.
__global__ __launch_bounds__(256) void conv3x3_k(const void* x, const void* w,
                                                 const void* bias, u16* out, const int* df){
  __shared__ float W[2304];
  int f = *df;
  int co = blockIdx.x, b = blockIdx.y, t = threadIdx.x;
  for(int i=t;i<2304;i+=256) W[i] = ldx(w, (long)co*2304 + i, f);
  __syncthreads();
  long xb = (long)b*256*3136;
  float bv = ldx(bias, co, f);
  for(int q=t;q<784;q+=256){
    int oy=q/28, ox=q%28;
    float acc=bv;
    for(int ci=0;ci<256;ci++){
      long xp = xb + (long)ci*3136;
      const float* wp = &W[ci*9];
      #pragma unroll
      for(int ky=0;ky<3;ky++){
        int iy=2*oy-1+ky;
        if((u32)iy>=56u) continue;
        #pragma unroll
        for(int kx=0;kx<3;kx++){
          int ix=2*ox-1+kx;
          if((u32)ix>=56u) continue;
          acc += ldx(x, xp + iy*56+ix, f)*wp[ky*3+kx];
        }
      }
    }
    out[((size_t)b*512+co)*784 + q] = f2bf(acc);
  }
}

// Grouped 3x3 s2 p1 conv (loc path): x=vmap is INTERNAL bf16; weights are inputs.
__global__ __launch_bounds__(256) void conv3x3g_k(const u16* __restrict__ x, const void* w,
                                                  const void* bias, u16* __restrict__ out, const int* df){
  __shared__ float W[576];
  int f = *df;
  int co = blockIdx.x, b = blockIdx.y, t = threadIdx.x;
  int g = co>>6;
  for(int i=t;i<576;i+=256) W[i] = ldx(w, (long)co*576 + i, f);
  __syncthreads();
  const u16* xb = x + ((size_t)b*512 + g*64)*3136;
  float bv = ldx(bias, co, f);
  for(int q=t;q<784;q+=256){
    int oy=q/28, ox=q%28;
    float acc=bv;
    for(int ci=0;ci<64;ci++){
      const u16* xp = xb + (size_t)ci*3136;
      const float* wp = &W[ci*9];
      #pragma unroll
      for(int ky=0;ky<3;ky++){
        int iy=2*oy-1+ky;
        if((u32)iy>=56u) continue;
        #pragma unroll
        for(int kx=0;kx<3;kx++){
          int ix=2*ox-1+kx;
          if((u32)ix>=56u) continue;
          acc += bf2f(xp[iy*56+ix])*wp[ky*3+kx];
        }
      }
    }
    out[((size_t)b*512+co)*784 + q] = f2bf(acc);
  }
}

// t = depthwise3x3s2(x) + q_local_b + x[:, :, ::2, ::2]  (all inputs)
__global__ __launch_bounds__(256) void qlocal_k(const void* x, const void* w,
                                                const void* bias, u16* __restrict__ out, const int* df){
  int f = *df;
  int id = blockIdx.x*256 + threadIdx.x;
  if(id >= 4*256*784) return;
  int q = id % 784; int r = id/784;
  int c = r % 256;  int b = r / 256;
  int oy = q/28, ox = q%28;
  long xp = (long)(b*256 + c)*3136;
  float acc = ldx(bias, c, f) + ldx(x, xp + (2*oy)*56 + 2*ox, f);
  #pragma unroll
  for(int ky=0;ky<3;ky++){
    int iy = 2*oy-1+ky;
    if((u32)iy>=56u) continue;
    #pragma unroll
    for(int kx=0;kx<3;kx++){
      int ix = 2*ox-1+kx;
      if((u32)ix>=56u) continue;
      acc += ldx(x, xp + iy*56+ix, f) * ldx(w, c*9+ky*3+kx, f);
    }
  }
  out[id] = f2bf(acc);
}

// Naive GEMM. A (weights) and bias are always harness inputs; B is an input
// only when bIn=1 (the k/v gemms read x directly).
__global__ __launch_bounds__(256) void gemm_naive_k(const void* A, const void* B,
                                                    u16* __restrict__ C, const void* bias,
                                                    int M, int N, int K, int AmodG,
                                                    long sAz, long sBz, long sCz, int sBiasz,
                                                    const int* df, int bIn){
  int f = *df;
  int fB = bIn ? f : 0;
  long id = (long)blockIdx.x*256 + threadIdx.x;
  if(id >= (long)M*N) return;
  int z = blockIdx.z;
  int zg = z % AmodG;
  int m = (int)(id / N), n = (int)(id % N);
  long aOff = (long)zg*sAz + (long)m*K;
  long bOff = (long)z*sBz + n;
  float acc = bias ? ldx(bias, zg*sBiasz + m, f) : 0.f;
  for(int k=0; k<K; k++) acc += ldx(A, aOff + k, f) * ldx(B, bOff + (long)k*N, fB);
  C[(size_t)z*sCz + id] = f2bf(acc);
}

// GroupNorm stats over internal bf16 buffers (unchanged).
__global__ __launch_bounds__(256) void gn_stats_k(const u16* __restrict__ x, float* __restrict__ st, int HW){
  int g = blockIdx.x, b = blockIdx.y, t = threadIdx.x;
  size_t base = (size_t)(b*512 + g*16)*HW;
  int tot = 16*HW;
  float s=0.f, ss=0.f;
  for(int e=t; e<tot; e+=256){ float v = bf2f(x[base+e]); s+=v; ss+=v*v; }
  __shared__ float rs[256], rq[256];
  rs[t]=s; rq[t]=ss; __syncthreads();
  for(int o=128;o>0;o>>=1){ if(t<o){ rs[t]+=rs[t+o]; rq[t]+=rq[t+o]; } __syncthreads(); }
  if(t==0){
    float m = rs[0]/(float)tot;
    float var = fmaxf(rq[0]/(float)tot - m*m, 0.f);
    st[(b*32+g)*2]   = m;
    st[(b*32+g)*2+1] = rsqrtf(var + 1e-5f);
  }
}

// GN affine apply. x/res internal bf16; w/bb inputs (dispatched); out is
// internal bf16 unless finalOut=1, in which case it follows the input dtype.
__global__ __launch_bounds__(256) void gn_aff_k(const u16* __restrict__ x, const float* __restrict__ st,
                                                const void* w, const void* bb,
                                                const u16* __restrict__ res, void* outp, int HW,
                                                const int* df, int finalOut){
  int f = *df;
  int id = blockIdx.x*256 + threadIdx.x;
  int tot8 = 4*512*HW/8;
  if(id>=tot8) return;
  size_t e = (size_t)id*8;
  int r = (int)(e / HW);
  int c = r % 512; int b = r / 512;
  int g = c>>4;
  float mean = st[(b*32+g)*2], rstd = st[(b*32+g)*2+1];
  float sw = ldx(w,c,f)*rstd;
  float sb = ldx(bb,c,f) - mean*sw;
  uint4 rv = *(const uint4*)(x + e);
  float fv[8]; unpk8(rv, fv);
  float o[8];
  #pragma unroll
  for(int j=0;j<8;j++) o[j] = fv[j]*sw + sb;
  if(res){
    uint4 rr = *(const uint4*)(res + e);
    float fr[8]; unpk8(rr, fr);
    #pragma unroll
    for(int j=0;j<8;j++) o[j] += fr[j];
  }
  if(finalOut && f){
    float* o32 = (float*)outp;
    #pragma unroll
    for(int j=0;j<8;j++) o32[e+j] = o[j];
  } else {
    u16 tmp[8];
    #pragma unroll
    for(int j=0;j<8;j++) tmp[j] = f2bf(o[j]);
    *(uint4*)((u16*)outp + e) = *(const uint4*)tmp;
  }
}

// Fused GN + l2norm(across heads) + transpose. x internal; w/bb inputs.
__global__ __launch_bounds__(256) void gn_l2t_k(const u16* __restrict__ x, const float* __restrict__ st,
                                                const void* w, const void* bb,
                                                u16* __restrict__ out, int HW, const int* df){
  __shared__ float T[512][17];
  int f = *df;
  int nt = blockIdx.x, b = blockIdx.y, t = threadIdx.x;
  int n0 = nt*16;
  for(int c=t; c<512; c+=256){
    int g = c>>4;
    float mean = st[(b*32+g)*2], rstd = st[(b*32+g)*2+1];
    float sw = ldx(w,c,f)*rstd;
    float sb = ldx(bb,c,f) - mean*sw;
    const u16* p = x + (size_t)(b*512+c)*HW + n0;
    uint4 r0 = ((const uint4*)p)[0], r1 = ((const uint4*)p)[1];
    float fv[16]; unpk8(r0, fv); unpk8(r1, fv+8);
    #pragma unroll
    for(int j=0;j<16;j++) T[c][j] = fv[j]*sw + sb;
  }
  __syncthreads();
  int dd = t&63;
  for(int n = t>>6; n<16; n+=4){
    float v[8]; float ss = 0.f;
    #pragma unroll
    for(int h=0;h<8;h++){ v[h] = T[h*64+dd][n]; ss += v[h]*v[h]; }
    float rn = 1.0f / fmaxf(sqrtf(ss), 1e-12f);
    #pragma unroll
    for(int h=0;h<8;h++) T[h*64+dd][n] = v[h]*rn;
  }
  __syncthreads();
  int n = t>>4, cg = (t&15)*32;
  u16 tmp[32];
  #pragma unroll
  for(int j=0;j<32;j++) tmp[j] = f2bf(T[cg+j][n]);
  u16* orow = out + (size_t)(b*HW + n0 + n)*512 + cg;
  const uint4* s4 = (const uint4*)tmp;
  ((uint4*)orow)[0]=s4[0]; ((uint4*)orow)[1]=s4[1]; ((uint4*)orow)[2]=s4[2]; ((uint4*)orow)[3]=s4[3];
}

// mbT[idx][o] = sum_i th1[o,i]*attn_biases[i,idx]  (both are inputs)
__global__ __launch_bounds__(256) void mbt_k(const void* th1, const void* ab,
                                             float* __restrict__ mbT, const int* df){
  int f = *df;
  int id = blockIdx.x*256 + threadIdx.x;
  if(id >= 3136*8) return;
  int o = id & 7; int idx = id >> 3;
  float s = 0.f;
  #pragma unroll
  for(int i=0;i<8;i++) s += ldx(th1, o*8+i, f) * ldx(ab, (long)i*3136+idx, f);
  mbT[id] = s;
}

// Fused attention (internal bf16 qnt/knt/vmap; th1/th2 are inputs).
template<int PHASE>
__global__ __launch_bounds__(256) void attn_k(const u16* __restrict__ qn_t, const u16* __restrict__ kn_t,
                                              const u16* __restrict__ vmap, const float* __restrict__ mbT,
                                              const void* th1w, const void* th2w,
                                              float* __restrict__ lbuf, u16* __restrict__ attno,
                                              const int* df){
  __shared__ float Q[8][512];
  __shared__ u16 KV[18432];
  __shared__ float A2[8][8][32];
  __shared__ float LINV[8][8];
  __shared__ float TH[128];
  int f = *df;
  int t = threadIdx.x;
  int b = blockIdx.z;
  int q0 = blockIdx.x*8;
  {
    int sq = t>>5, sc = (t&31)*16;
    const u16* p = qn_t + (size_t)(b*784 + q0+sq)*512 + sc;
    uint4 r0 = ((const uint4*)p)[0], r1 = ((const uint4*)p)[1];
    unpk8(r0, &Q[sq][sc]); unpk8(r1, &Q[sq][sc+8]);
  }
  if(t<128) TH[t] = (t<64) ? ldx(th1w, t, f) : ldx(th2w, t-64, f);
  if(PHASE==1 && t<64){
    float lv = lbuf[(size_t)(b*8+(t>>3))*784 + q0 + (t&7)];
    LINV[t>>3][t&7] = (lv > 0.f) ? 1.0f/lv : 0.f;
  }
  __syncthreads();

  int ql = t>>5, nl = t&31;
  int qg = q0 + ql;
  int qy2 = 2*(qg/28), qx2 = 2*(qg%28);
  float lacc[8];
  float oacc[8][2];
  #pragma unroll
  for(int j=0;j<8;j++){ lacc[j]=0.f; oacc[j][0]=0.f; oacc[j][1]=0.f; }
  int o2 = t>>5, dp = t&31;

  for(int nt=0; nt<98; nt++){
    int n0 = nt*32;
    __syncthreads();
    {
      int knl = t>>3, kc = (t&7)*64;
      const uint4* p = (const uint4*)(kn_t + (size_t)(b*3136 + n0+knl)*512 + kc);
      uint4* d = (uint4*)&KV[knl*520 + kc];
      #pragma unroll
      for(int j=0;j<8;j++) d[j] = p[j];
    }
    __syncthreads();
    float dot[8];
    const u16* kr = &KV[nl*520];
    const float* qr = &Q[ql][0];
    #pragma unroll
    for(int i=0;i<8;i++){
      float a = 0.f;
      #pragma unroll
      for(int c8=0;c8<8;c8++){
        int base = i*64 + c8*8;
        uint4 kv = *(const uint4*)(kr + base);
        float kf[8]; unpk8(kv, kf);
        float4 qa = *(const float4*)(qr+base);
        float4 qb = *(const float4*)(qr+base+4);
        a += qa.x*kf[0]+qa.y*kf[1]+qa.z*kf[2]+qa.w*kf[3]
           + qb.x*kf[4]+qb.y*kf[5]+qb.z*kf[6]+qb.w*kf[7];
      }
      dot[i] = a;
    }
    int n = n0 + nl;
    int ny = n/56, nx = n%56;
    int oy = iabs(qy2-ny), ox = iabs(qx2-nx);
    const float* mb = mbT + (oy*56+ox)*8;
    float p8[8];
    #pragma unroll
    for(int o=0;o<8;o++){
      float s = 0.f;
      #pragma unroll
      for(int i=0;i<8;i++) s += TH[o*8+i]*dot[i];
      p8[o] = __expf(fminf(s*0.125f + mb[o], 60.f));
    }
    if(PHASE==0){
      #pragma unroll
      for(int o=0;o<8;o++) lacc[o] += p8[o];
    } else {
      float pn[8];
      #pragma unroll
      for(int o=0;o<8;o++) pn[o] = p8[o]*LINV[o][ql];
      #pragma unroll
      for(int oo=0;oo<8;oo++){
        float s = 0.f;
        #pragma unroll
        for(int o=0;o<8;o++) s += TH[64+oo*8+o]*pn[o];
        A2[oo][ql][nl] = s;
      }
      __syncthreads();
      for(int c=t; c<512; c+=256){
        const uint4* p = (const uint4*)(vmap + (size_t)(b*512+c)*3136 + n0);
        uint4 r0=p[0], r1=p[1], r2=p[2], r3=p[3];
        u32* d = (u32*)&KV[c*36];
        d[0]=r0.x; d[1]=r0.y; d[2]=r0.z; d[3]=r0.w;
        d[4]=r1.x; d[5]=r1.y; d[6]=r1.z; d[7]=r1.w;
        d[8]=r2.x; d[9]=r2.y; d[10]=r2.z; d[11]=r2.w;
        d[12]=r3.x; d[13]=r3.y; d[14]=r3.z; d[15]=r3.w;
      }
      __syncthreads();
      int c0 = o2*64 + dp;
      #pragma unroll
      for(int n4=0;n4<8;n4++){
        uint2 rv0 = *(const uint2*)&KV[c0*36 + n4*4];
        uint2 rv1 = *(const uint2*)&KV[(c0+32)*36 + n4*4];
        float v0[4], v1[4]; unpk4(rv0, v0); unpk4(rv1, v1);
        #pragma unroll
        for(int q=0;q<8;q++){
          const float4 aq = *(const float4*)&A2[o2][q][n4*4];
          oacc[q][0] += aq.x*v0[0]+aq.y*v0[1]+aq.z*v0[2]+aq.w*v0[3];
          oacc[q][1] += aq.x*v1[0]+aq.y*v1[1]+aq.z*v1[2]+aq.w*v1[3];
        }
      }
    }
  }
  if(PHASE==0){
    #pragma unroll
    for(int o=0;o<8;o++){
      float v = lacc[o];
      v += __shfl_xor(v,1); v += __shfl_xor(v,2); v += __shfl_xor(v,4);
      v += __shfl_xor(v,8); v += __shfl_xor(v,16);
      if(nl==0) lbuf[(size_t)(b*8+o)*784 + qg] = v;
    }
  } else {
    int c0 = o2*64 + dp;
    u16 tmp[8];
    #pragma unroll
    for(int q=0;q<8;q++) tmp[q] = f2bf(oacc[q][0]);
    *(uint4*)(attno + (size_t)(b*512+c0)*784 + q0) = *(const uint4*)tmp;
    #pragma unroll
    for(int q=0;q<8;q++) tmp[q] = f2bf(oacc[q][1]);
    *(uint4*)(attno + (size_t)(b*512+c0+32)*784 + q0) = *(const uint4*)tmp;
  }
}

// h = hardswish(attno + vlocal)  (internal only)
__global__ __launch_bounds__(256) void hs_add_k(const u16* __restrict__ a, const u16* __restrict__ bsrc,
                                                u16* __restrict__ out){
  int id = blockIdx.x*256 + threadIdx.x;
  const int tot8 = 4*512*784/8;
  if(id>=tot8) return;
  size_t e = (size_t)id*8;
  uint4 ra = *(const uint4*)(a+e), rb = *(const uint4*)(bsrc+e);
  float fa[8], fb[8]; unpk8(ra, fa); unpk8(rb, fb);
  u16 tmp[8];
  #pragma unroll
  for(int j=0;j<8;j++){
    float s = fa[j]+fb[j];
    float cl = fminf(fmaxf(s+3.f, 0.f), 6.f);
    tmp[j] = f2bf(s*cl*(1.f/6.f));
  }
  *(uint4*)(out+e) = *(const uint4*)tmp;
}

// ---------------------------------------------------------------------------
extern "C" void kernel_launch(void* const* d_in, const int* in_sizes, int n_in,
                              void* d_out, int out_size, void* d_ws, size_t ws_size,
                              hipStream_t stream){
  u16* out16 = (u16*)d_out;

  if(n_in != 28){ sentinel_k<<<dim3(1),64,0,stream>>>(out16, 90112.f); return; }
  if(in_sizes[0]  != 3211264){ sentinel_k<<<dim3(1),64,0,stream>>>(out16, 88064.f); return; }
  if(in_sizes[22] != 1179648){ sentinel_k<<<dim3(1),64,0,stream>>>(out16, 81920.f); return; }
  if(out_size != 1605632){ sentinel_k<<<dim3(1),64,0,stream>>>(out16, 75776.f); return; }

  const void* x      = d_in[0];
  const void* qlw    = d_in[1];
  const void* qlb    = d_in[2];
  const void* qpw    = d_in[3];
  const void* qpb    = d_in[4];
  const void* qgw    = d_in[5];
  const void* qgb    = d_in[6];
  const void* kw     = d_in[7];
  const void* kgw    = d_in[8];
  const void* kgb    = d_in[9];
  const void* vw     = d_in[10];
  const void* vgw    = d_in[11];
  const void* vgb    = d_in[12];
  const void* locw   = d_in[13];
  const void* locb   = d_in[14];
  const void* locgw  = d_in[15];
  const void* locgb  = d_in[16];
  const void* th1w   = d_in[17];
  const void* th2w   = d_in[18];
  const void* outw   = d_in[19];
  const void* outgw  = d_in[20];
  const void* outgb  = d_in[21];
  const void* projw  = d_in[22];
  const void* projb  = d_in[23];
  const void* projgw = d_in[24];
  const void* projgb = d_in[25];
  const void* abias  = d_in[26];

  char* ws = (char*)d_ws;
  size_t off = 0;
  auto alloc = [&](size_t bytes)->void*{
    void* p = ws + off;
    off += (bytes + 255) & ~(size_t)255;
    return p;
  };
  const size_t SM_SMALL = (size_t)4*512*784*2;
  const size_t SM_BIG   = (size_t)4*512*3136*2;
  u16* arenaB  = (u16*)alloc(SM_BIG);     // kpre -> vpre -> opre
  u16* arenaC  = (u16*)alloc(SM_SMALL);   // projpre -> qpre -> locpre
  u16* tbuf    = (u16*)alloc((size_t)4*256*784*2);
  u16* xproj   = (u16*)alloc(SM_SMALL);
  u16* qnt     = (u16*)alloc((size_t)4*784*512*2);
  u16* knt     = (u16*)alloc((size_t)4*3136*512*2);
  u16* vmap    = (u16*)alloc(SM_BIG);
  u16* vloc    = (u16*)alloc(SM_SMALL);
  u16* attno   = (u16*)alloc(SM_SMALL);
  u16* hbuf    = (u16*)alloc(SM_SMALL);
  float* mbT   = (float*)alloc((size_t)3136*8*4);
  float* lbuf  = (float*)alloc((size_t)4*8*784*4);
  int*   dflag = (int*)alloc(256);
  float* st0   = (float*)alloc(4*32*2*4);
  float* st1   = (float*)alloc(4*32*2*4);
  float* st2   = (float*)alloc(4*32*2*4);
  float* st3   = (float*)alloc(4*32*2*4);
  float* st4   = (float*)alloc(4*32*2*4);
  float* st5   = (float*)alloc(4*32*2*4);

  if(off > ws_size){
    float code = 100000.f + (float)(ws_size >> 20) * 100.f;
    sentinel_k<<<dim3(1),64,0,stream>>>(out16, code);
    return;
  }

  u16* projpre = arenaC;
  u16* qpre    = arenaC;
  u16* locpre  = arenaC;
  u16* kpre    = arenaB;
  u16* vpre    = arenaB;
  u16* opre    = arenaB;

  // dtype probe: decides fp32 vs bf16 interpretation for ALL input reads
  // and the final output write.
  detect_k<<<dim3(1),256,0,stream>>>(x, dflag);

  // x_proj = GN(conv3x3s2(x, proj_w) + proj_b)
  conv3x3_k<<<dim3(512,4),256,0,stream>>>(x, projw, projb, projpre, dflag);
  gn_stats_k<<<dim3(32,4),256,0,stream>>>(projpre, st0, 784);
  gn_aff_k<<<dim3(784),256,0,stream>>>(projpre, st0, projgw, projgb, nullptr, xproj, 784, dflag, 0);

  // q = l2norm(GN(conv1x1(depthwise+pool) + b)) -> [q][c]
  qlocal_k<<<dim3((4*256*784)/256),256,0,stream>>>(x, qlw, qlb, tbuf, dflag);
  gemm_naive_k<<<dim3((512*784+255)/256,1,4),256,0,stream>>>(qpw, tbuf, qpre, qpb,
      512,784,256, 1, 0, (long)256*784, (long)512*784, 0, dflag, 0);
  gn_stats_k<<<dim3(32,4),256,0,stream>>>(qpre, st1, 784);
  gn_l2t_k<<<dim3(49,4),256,0,stream>>>(qpre, st1, qgw, qgb, qnt, 784, dflag);

  // k = l2norm(GN(conv1x1(x))) -> [n][c]
  gemm_naive_k<<<dim3((512*3136+255)/256,1,4),256,0,stream>>>(kw, x, kpre, nullptr,
      512,3136,256, 1, 0, (long)256*3136, (long)512*3136, 0, dflag, 1);
  gn_stats_k<<<dim3(32,4),256,0,stream>>>(kpre, st2, 3136);
  gn_l2t_k<<<dim3(196,4),256,0,stream>>>(kpre, st2, kgw, kgb, knt, 3136, dflag);

  // v_map = GN(conv1x1(x))
  gemm_naive_k<<<dim3((512*3136+255)/256,1,4),256,0,stream>>>(vw, x, vpre, nullptr,
      512,3136,256, 1, 0, (long)256*3136, (long)512*3136, 0, dflag, 1);
  gn_stats_k<<<dim3(32,4),256,0,stream>>>(vpre, st3, 3136);
  gn_aff_k<<<dim3(3136),256,0,stream>>>(vpre, st3, vgw, vgb, nullptr, vmap, 3136, dflag, 0);

  // v_local = GN(groupconv3x3s2(v_map) + loc_b)
  conv3x3g_k<<<dim3(512,4),256,0,stream>>>(vmap, locw, locb, locpre, dflag);
  gn_stats_k<<<dim3(32,4),256,0,stream>>>(locpre, st4, 784);
  gn_aff_k<<<dim3(784),256,0,stream>>>(locpre, st4, locgw, locgb, nullptr, vloc, 784, dflag, 0);

  // attention (two-pass, fused, clamped max-free softmax)
  mbt_k<<<dim3(98),256,0,stream>>>(th1w, abias, mbT, dflag);
  attn_k<0><<<dim3(98,1,4),256,0,stream>>>(qnt, knt, vmap, mbT, th1w, th2w, lbuf, nullptr, dflag);
  attn_k<1><<<dim3(98,1,4),256,0,stream>>>(qnt, knt, vmap, mbT, th1w, th2w, lbuf, attno, dflag);

  // out = GN(conv1x1(hardswish(attn_out + v_local))) + x_proj
  hs_add_k<<<dim3(784),256,0,stream>>>(attno, vloc, hbuf);
  gemm_naive_k<<<dim3((512*784+255)/256,1,4),256,0,stream>>>(outw, hbuf, opre, nullptr,
      512,784,512, 1, 0, (long)512*784, (long)512*784, 0, dflag, 0);
  gn_stats_k<<<dim3(32,4),256,0,stream>>>(opre, st5, 784);
  gn_aff_k<<<dim3(784),256,0,stream>>>(opre, st5, outgw, outgb, xproj, d_out, 784, dflag, 1);

  // tri-state: NaN in out -> 4096 (diagnostic), else untouched
  sanitize_k<<<dim3(1024),256,0,stream>>>(d_out, (long)out_size, dflag);
}

// Round 10
// 2818.890 us; speedup vs baseline: 2.5298x; 2.5298x over previous
//
#include <hip/hip_runtime.h>
#include <stdint.h>

typedef unsigned short u16;
typedef unsigned int u32;
typedef __attribute__((ext_vector_type(8))) short bf16x8;
typedef __attribute__((ext_vector_type(4))) float f32x4;

#define DEV static __device__ __forceinline__

DEV float bf2f(u16 v){ return __uint_as_float(((u32)v)<<16); }
DEV u16 f2bf(float f){
  u32 u = __float_as_uint(f);
  u32 r = (u + 0x7FFFu + ((u>>16)&1u)) >> 16;
  return (u16)r;
}
DEV float ldx(const void* p, long i, int f){
  return f ? ((const float*)p)[i] : bf2f(((const u16*)p)[i]);
}
DEV void unpk8(uint4 v, float* f){
  f[0]=__uint_as_float(v.x<<16); f[1]=__uint_as_float(v.x&0xFFFF0000u);
  f[2]=__uint_as_float(v.y<<16); f[3]=__uint_as_float(v.y&0xFFFF0000u);
  f[4]=__uint_as_float(v.z<<16); f[5]=__uint_as_float(v.z&0xFFFF0000u);
  f[6]=__uint_as_float(v.w<<16); f[7]=__uint_as_float(v.w&0xFFFF0000u);
}
DEV void unpk4(uint2 v, float* f){
  f[0]=__uint_as_float(v.x<<16); f[1]=__uint_as_float(v.x&0xFFFF0000u);
  f[2]=__uint_as_float(v.y<<16); f[3]=__uint_as_float(v.y&0xFFFF0000u);
}
DEV int iabs(int a){ return a<0? -a : a; }

// ======================= dtype probe / guards =======================
__global__ void detect_k(const void* x, int* dflag){
  const u16* p = (const u16*)x;
  int t = threadIdx.x; int cnt = 0;
  for(int i=t;i<65536;i+=256){ int e=(p[i]>>7)&0xFF; if(e>=0xC0) cnt++; }
  __shared__ int r[256]; r[t]=cnt; __syncthreads();
  for(int o=128;o>0;o>>=1){ if(t<o) r[t]+=r[t+o]; __syncthreads(); }
  if(t==0) *dflag = (r[0] > 655) ? 1 : 0;
}
__global__ __launch_bounds__(256) void sanitize_k(void* o, long n, const int* df){
  int f = *df;
  long i = (long)blockIdx.x*256 + threadIdx.x;
  long st = (long)gridDim.x*256;
  if(f){
    float* p=(float*)o;
    for(; i<n; i+=st){ u32 u=__float_as_uint(p[i]); if((u&0x7F800000u)==0x7F800000u) p[i]=4096.f; }
  } else {
    u16* p=(u16*)o;
    u16 c = f2bf(4096.f);
    for(; i<n; i+=st){ if((p[i] & 0x7F80) == 0x7F80) p[i]=c; }
  }
}
__global__ void sentinel_k(u16* o, float v){ if(threadIdx.x==0) o[0] = f2bf(v); }

// ======================= data movement =======================
// x [b][C][HW] (input dtype) -> xT [b][HW][C] bf16. 32x32 LDS tile.
__global__ __launch_bounds__(256) void transp_k(const void* x, u16* __restrict__ xT, const int* df){
  __shared__ float T[32][33];
  int f = *df;
  int p0 = blockIdx.x*32, c0 = blockIdx.y*32, b = blockIdx.z;
  int tx = threadIdx.x & 31, ty = threadIdx.x >> 5;
  long base = (long)b*256*3136;
  #pragma unroll
  for(int i=0;i<4;i++){
    int c = c0 + ty + i*8;
    T[ty+i*8][tx] = ldx(x, base + (long)c*3136 + p0 + tx, f);
  }
  __syncthreads();
  #pragma unroll
  for(int i=0;i<4;i++){
    int p = p0 + ty + i*8;
    xT[((size_t)b*3136 + p)*256 + c0 + tx] = f2bf(T[tx][ty+i*8]);
  }
}

// im2col (3x3 s2 p1), BT convention: out[q][ci*9+k], one batch per launch.
// in: element offset `off` into a [Cin][56][56] image; isInput selects dtype.
__global__ __launch_bounds__(256) void im2col_bt_k(const void* in, long off, u16* __restrict__ out,
                                                   int Cin, int isInput, const int* df){
  int f = isInput ? *df : 0;
  int K9 = Cin*9;
  int total = 784*K9;
  int id = blockIdx.x*256 + threadIdx.x;
  if(id>=total) return;
  int q = id / K9, r = id % K9;
  int ci = r/9, k = r%9;
  int oy=q/28, ox=q%28, ky=k/3, kx=k%3;
  int iy=2*oy-1+ky, ix=2*ox-1+kx;
  float v = 0.f;
  if((u32)iy<56u && (u32)ix<56u) v = ldx(in, off + (long)ci*3136 + iy*56+ix, f);
  out[id] = f2bf(v);
}

// t = depthwise3x3s2(x) + q_local_b + pool, written TRANSPOSED: tbufT[b][q][c]
__global__ __launch_bounds__(256) void qlocal_bt_k(const void* x, const void* w,
                                                   const void* bias, u16* __restrict__ outT, const int* df){
  int f = *df;
  int id = blockIdx.x*256 + threadIdx.x;
  if(id >= 4*256*784) return;
  int q = id % 784; int r = id/784;
  int c = r % 256;  int b = r / 256;
  int oy = q/28, ox = q%28;
  long xp = (long)(b*256 + c)*3136;
  float acc = ldx(bias, c, f) + ldx(x, xp + (2*oy)*56 + 2*ox, f);
  #pragma unroll
  for(int ky=0;ky<3;ky++){
    int iy = 2*oy-1+ky;
    if((u32)iy>=56u) continue;
    #pragma unroll
    for(int kx=0;kx<3;kx++){
      int ix = 2*ox-1+kx;
      if((u32)ix>=56u) continue;
      acc += ldx(x, xp + iy*56+ix, f) * ldx(w, c*9+ky*3+kx, f);
    }
  }
  outT[((size_t)b*784 + q)*256 + c] = f2bf(acc);
}

// hardswish(attno + vloc) -> hbufT[b][q][c] (fused transpose, 32x32 tile)
__global__ __launch_bounds__(256) void hs_addT_k(const u16* __restrict__ a, const u16* __restrict__ bsrc,
                                                 u16* __restrict__ outT){
  __shared__ float T[32][33];
  int q0 = blockIdx.x*32, c0 = blockIdx.y*32, b = blockIdx.z;
  int tx = threadIdx.x&31, ty = threadIdx.x>>5;
  #pragma unroll
  for(int i=0;i<4;i++){
    int c = c0+ty+i*8;
    int q = q0+tx;
    float s = 0.f;
    if(q < 784){
      size_t e = ((size_t)b*512 + c)*784 + q;
      s = bf2f(a[e]) + bf2f(bsrc[e]);
      float cl = fminf(fmaxf(s+3.f,0.f),6.f);
      s = s*cl*(1.f/6.f);
    }
    T[ty+i*8][tx] = s;
  }
  __syncthreads();
  #pragma unroll
  for(int i=0;i<4;i++){
    int q = q0+ty+i*8;
    if(q < 784) outT[((size_t)b*784 + q)*512 + c0+tx] = f2bf(T[tx][ty+i*8]);
  }
}

// ======================= MFMA GEMM (BT convention) =======================
// C[z][m][n] = sum_k A[z*sA + m*K + k] * BT[z*sB + n*ldB + k]  (+bias)
// A: weights, input dtype (fp32/bf16, converted during LDS staging).
// BT: bf16 ws activations [N][ldB]. C: bf16 [M][N]. M%64==0, K%32==0, N%16==0.
// Block 256 thr = 4 waves; tile 64m x 64n; wave w -> rows [16w,16w+16).
__global__ __launch_bounds__(256) void gemm_mfma_k(const void* A, const u16* __restrict__ BT,
                                                   u16* __restrict__ C, const void* bias,
                                                   int M, int N, int K, int ldB,
                                                   long sA, long sB, long sC, int sBias,
                                                   const int* df){
  __shared__ u16 As[64][40];   // +8 pad: 2-way max bank aliasing (free)
  __shared__ u16 Bs[64][40];
  int f = *df;
  int z = blockIdx.z;
  long aBase = (long)z*sA;
  const u16* Bp = BT + (size_t)z*sB;
  u16* Cp = C + (size_t)z*sC;
  int n0 = blockIdx.x*64, m0 = blockIdx.y*64;
  int t = threadIdx.x;
  int sm = t>>2, sk = (t&3)*8;    // staging: row 0..63, k-offset {0,8,16,24}
  int w = t>>6, l = t&63;
  int lm = l&15, lq = l>>4;
  f32x4 acc0={0.f,0.f,0.f,0.f}, acc1=acc0, acc2=acc0, acc3=acc0;
  bool bok = (n0 + sm) < N;
  for(int kk=0; kk<K; kk+=32){
    { // A stage (dtype-dispatched convert)
      long off = aBase + (long)(m0+sm)*K + kk + sk;
      if(f){
        const float* Af = (const float*)A;
        float4 v0 = *(const float4*)(Af+off);
        float4 v1 = *(const float4*)(Af+off+4);
        u16 tmp[8];
        tmp[0]=f2bf(v0.x); tmp[1]=f2bf(v0.y); tmp[2]=f2bf(v0.z); tmp[3]=f2bf(v0.w);
        tmp[4]=f2bf(v1.x); tmp[5]=f2bf(v1.y); tmp[6]=f2bf(v1.z); tmp[7]=f2bf(v1.w);
        *(uint4*)&As[sm][sk] = *(const uint4*)tmp;
      } else {
        *(uint4*)&As[sm][sk] = *(const uint4*)((const u16*)A + off);
      }
    }
    { // BT stage
      uint4 v = {0u,0u,0u,0u};
      if(bok) v = *(const uint4*)(Bp + (size_t)(n0+sm)*ldB + kk + sk);
      *(uint4*)&Bs[sm][sk] = v;
    }
    __syncthreads();
    bf16x8 a  = *(const bf16x8*)&As[w*16 + lm][lq*8];
    bf16x8 b0 = *(const bf16x8*)&Bs[ 0 + lm][lq*8];
    bf16x8 b1 = *(const bf16x8*)&Bs[16 + lm][lq*8];
    bf16x8 b2 = *(const bf16x8*)&Bs[32 + lm][lq*8];
    bf16x8 b3 = *(const bf16x8*)&Bs[48 + lm][lq*8];
    acc0 = __builtin_amdgcn_mfma_f32_16x16x32_bf16(a, b0, acc0, 0,0,0);
    acc1 = __builtin_amdgcn_mfma_f32_16x16x32_bf16(a, b1, acc1, 0,0,0);
    acc2 = __builtin_amdgcn_mfma_f32_16x16x32_bf16(a, b2, acc2, 0,0,0);
    acc3 = __builtin_amdgcn_mfma_f32_16x16x32_bf16(a, b3, acc3, 0,0,0);
    __syncthreads();
  }
  // epilogue: D row = m0 + 16w + 4*lq + r, col = n0 + 16*nb + lm
  f32x4 aa[4] = {acc0, acc1, acc2, acc3};
  int mloc = w*16 + lq*4;
  #pragma unroll
  for(int nb=0;nb<4;nb++){
    if(n0 + nb*16 >= N) break;
    int n = n0 + nb*16 + lm;
    #pragma unroll
    for(int r=0;r<4;r++){
      int m = m0 + mloc + r;
      float v = aa[nb][r];
      if(bias) v += ldx(bias, (long)z*sBias + m, f);
      Cp[(size_t)m*N + n] = f2bf(v);
    }
  }
}

// ======================= GN / attention (validated R9 forms) =======================
__global__ __launch_bounds__(256) void gn_stats_k(const u16* __restrict__ x, float* __restrict__ st, int HW){
  int g = blockIdx.x, b = blockIdx.y, t = threadIdx.x;
  size_t base = (size_t)(b*512 + g*16)*HW;
  int tot = 16*HW;
  float s=0.f, ss=0.f;
  for(int e=t; e<tot; e+=256){ float v = bf2f(x[base+e]); s+=v; ss+=v*v; }
  __shared__ float rs[256], rq[256];
  rs[t]=s; rq[t]=ss; __syncthreads();
  for(int o=128;o>0;o>>=1){ if(t<o){ rs[t]+=rs[t+o]; rq[t]+=rq[t+o]; } __syncthreads(); }
  if(t==0){
    float m = rs[0]/(float)tot;
    float var = fmaxf(rq[0]/(float)tot - m*m, 0.f);
    st[(b*32+g)*2]   = m;
    st[(b*32+g)*2+1] = rsqrtf(var + 1e-5f);
  }
}

__global__ __launch_bounds__(256) void gn_aff_k(const u16* __restrict__ x, const float* __restrict__ st,
                                                const void* w, const void* bb,
                                                const u16* __restrict__ res, void* outp, int HW,
                                                const int* df, int finalOut){
  int f = *df;
  int id = blockIdx.x*256 + threadIdx.x;
  int tot8 = 4*512*HW/8;
  if(id>=tot8) return;
  size_t e = (size_t)id*8;
  int r = (int)(e / HW);
  int c = r % 512; int b = r / 512;
  int g = c>>4;
  float mean = st[(b*32+g)*2], rstd = st[(b*32+g)*2+1];
  float sw = ldx(w,c,f)*rstd;
  float sb = ldx(bb,c,f) - mean*sw;
  uint4 rv = *(const uint4*)(x + e);
  float fv[8]; unpk8(rv, fv);
  float o[8];
  #pragma unroll
  for(int j=0;j<8;j++) o[j] = fv[j]*sw + sb;
  if(res){
    uint4 rr = *(const uint4*)(res + e);
    float fr[8]; unpk8(rr, fr);
    #pragma unroll
    for(int j=0;j<8;j++) o[j] += fr[j];
  }
  if(finalOut && f){
    float* o32 = (float*)outp;
    #pragma unroll
    for(int j=0;j<8;j++) o32[e+j] = o[j];
  } else {
    u16 tmp[8];
    #pragma unroll
    for(int j=0;j<8;j++) tmp[j] = f2bf(o[j]);
    *(uint4*)((u16*)outp + e) = *(const uint4*)tmp;
  }
}

__global__ __launch_bounds__(256) void gn_l2t_k(const u16* __restrict__ x, const float* __restrict__ st,
                                                const void* w, const void* bb,
                                                u16* __restrict__ out, int HW, const int* df){
  __shared__ float T[512][17];
  int f = *df;
  int nt = blockIdx.x, b = blockIdx.y, t = threadIdx.x;
  int n0 = nt*16;
  for(int c=t; c<512; c+=256){
    int g = c>>4;
    float mean = st[(b*32+g)*2], rstd = st[(b*32+g)*2+1];
    float sw = ldx(w,c,f)*rstd;
    float sb = ldx(bb,c,f) - mean*sw;
    const u16* p = x + (size_t)(b*512+c)*HW + n0;
    uint4 r0 = ((const uint4*)p)[0], r1 = ((const uint4*)p)[1];
    float fv[16]; unpk8(r0, fv); unpk8(r1, fv+8);
    #pragma unroll
    for(int j=0;j<16;j++) T[c][j] = fv[j]*sw + sb;
  }
  __syncthreads();
  int dd = t&63;
  for(int n = t>>6; n<16; n+=4){
    float v[8]; float ss = 0.f;
    #pragma unroll
    for(int h=0;h<8;h++){ v[h] = T[h*64+dd][n]; ss += v[h]*v[h]; }
    float rn = 1.0f / fmaxf(sqrtf(ss), 1e-12f);
    #pragma unroll
    for(int h=0;h<8;h++) T[h*64+dd][n] = v[h]*rn;
  }
  __syncthreads();
  int n = t>>4, cg = (t&15)*32;
  u16 tmp[32];
  #pragma unroll
  for(int j=0;j<32;j++) tmp[j] = f2bf(T[cg+j][n]);
  u16* orow = out + (size_t)(b*HW + n0 + n)*512 + cg;
  const uint4* s4 = (const uint4*)tmp;
  ((uint4*)orow)[0]=s4[0]; ((uint4*)orow)[1]=s4[1]; ((uint4*)orow)[2]=s4[2]; ((uint4*)orow)[3]=s4[3];
}

__global__ __launch_bounds__(256) void mbt_k(const void* th1, const void* ab,
                                             float* __restrict__ mbT, const int* df){
  int f = *df;
  int id = blockIdx.x*256 + threadIdx.x;
  if(id >= 3136*8) return;
  int o = id & 7; int idx = id >> 3;
  float s = 0.f;
  #pragma unroll
  for(int i=0;i<8;i++) s += ldx(th1, o*8+i, f) * ldx(ab, (long)i*3136+idx, f);
  mbT[id] = s;
}

template<int PHASE>
__global__ __launch_bounds__(256) void attn_k(const u16* __restrict__ qn_t, const u16* __restrict__ kn_t,
                                              const u16* __restrict__ vmap, const float* __restrict__ mbT,
                                              const void* th1w, const void* th2w,
                                              float* __restrict__ lbuf, u16* __restrict__ attno,
                                              const int* df){
  __shared__ float Q[8][512];
  __shared__ u16 KV[18432];
  __shared__ float A2[8][8][32];
  __shared__ float LINV[8][8];
  __shared__ float TH[128];
  int f = *df;
  int t = threadIdx.x;
  int b = blockIdx.z;
  int q0 = blockIdx.x*8;
  {
    int sq = t>>5, sc = (t&31)*16;
    const u16* p = qn_t + (size_t)(b*784 + q0+sq)*512 + sc;
    uint4 r0 = ((const uint4*)p)[0], r1 = ((const uint4*)p)[1];
    unpk8(r0, &Q[sq][sc]); unpk8(r1, &Q[sq][sc+8]);
  }
  if(t<128) TH[t] = (t<64) ? ldx(th1w, t, f) : ldx(th2w, t-64, f);
  if(PHASE==1 && t<64){
    float lv = lbuf[(size_t)(b*8+(t>>3))*784 + q0 + (t&7)];
    LINV[t>>3][t&7] = (lv > 0.f) ? 1.0f/lv : 0.f;
  }
  __syncthreads();

  int ql = t>>5, nl = t&31;
  int qg = q0 + ql;
  int qy2 = 2*(qg/28), qx2 = 2*(qg%28);
  float lacc[8];
  float oacc[8][2];
  #pragma unroll
  for(int j=0;j<8;j++){ lacc[j]=0.f; oacc[j][0]=0.f; oacc[j][1]=0.f; }
  int o2 = t>>5, dp = t&31;

  for(int nt=0; nt<98; nt++){
    int n0 = nt*32;
    __syncthreads();
    {
      int knl = t>>3, kc = (t&7)*64;
      const uint4* p = (const uint4*)(kn_t + (size_t)(b*3136 + n0+knl)*512 + kc);
      uint4* d = (uint4*)&KV[knl*520 + kc];
      #pragma unroll
      for(int j=0;j<8;j++) d[j] = p[j];
    }
    __syncthreads();
    float dot[8];
    const u16* kr = &KV[nl*520];
    const float* qr = &Q[ql][0];
    #pragma unroll
    for(int i=0;i<8;i++){
      float a = 0.f;
      #pragma unroll
      for(int c8=0;c8<8;c8++){
        int base = i*64 + c8*8;
        uint4 kv = *(const uint4*)(kr + base);
        float kf[8]; unpk8(kv, kf);
        float4 qa = *(const float4*)(qr+base);
        float4 qb = *(const float4*)(qr+base+4);
        a += qa.x*kf[0]+qa.y*kf[1]+qa.z*kf[2]+qa.w*kf[3]
           + qb.x*kf[4]+qb.y*kf[5]+qb.z*kf[6]+qb.w*kf[7];
      }
      dot[i] = a;
    }
    int n = n0 + nl;
    int ny = n/56, nx = n%56;
    int oy = iabs(qy2-ny), ox = iabs(qx2-nx);
    const float* mb = mbT + (oy*56+ox)*8;
    float p8[8];
    #pragma unroll
    for(int o=0;o<8;o++){
      float s = 0.f;
      #pragma unroll
      for(int i=0;i<8;i++) s += TH[o*8+i]*dot[i];
      p8[o] = __expf(fminf(s*0.125f + mb[o], 60.f));
    }
    if(PHASE==0){
      #pragma unroll
      for(int o=0;o<8;o++) lacc[o] += p8[o];
    } else {
      float pn[8];
      #pragma unroll
      for(int o=0;o<8;o++) pn[o] = p8[o]*LINV[o][ql];
      #pragma unroll
      for(int oo=0;oo<8;oo++){
        float s = 0.f;
        #pragma unroll
        for(int o=0;o<8;o++) s += TH[64+oo*8+o]*pn[o];
        A2[oo][ql][nl] = s;
      }
      __syncthreads();
      for(int c=t; c<512; c+=256){
        const uint4* p = (const uint4*)(vmap + (size_t)(b*512+c)*3136 + n0);
        uint4 r0=p[0], r1=p[1], r2=p[2], r3=p[3];
        u32* d = (u32*)&KV[c*36];
        d[0]=r0.x; d[1]=r0.y; d[2]=r0.z; d[3]=r0.w;
        d[4]=r1.x; d[5]=r1.y; d[6]=r1.z; d[7]=r1.w;
        d[8]=r2.x; d[9]=r2.y; d[10]=r2.z; d[11]=r2.w;
        d[12]=r3.x; d[13]=r3.y; d[14]=r3.z; d[15]=r3.w;
      }
      __syncthreads();
      int c0 = o2*64 + dp;
      #pragma unroll
      for(int n4=0;n4<8;n4++){
        uint2 rv0 = *(const uint2*)&KV[c0*36 + n4*4];
        uint2 rv1 = *(const uint2*)&KV[(c0+32)*36 + n4*4];
        float v0[4], v1[4]; unpk4(rv0, v0); unpk4(rv1, v1);
        #pragma unroll
        for(int q=0;q<8;q++){
          const float4 aq = *(const float4*)&A2[o2][q][n4*4];
          oacc[q][0] += aq.x*v0[0]+aq.y*v0[1]+aq.z*v0[2]+aq.w*v0[3];
          oacc[q][1] += aq.x*v1[0]+aq.y*v1[1]+aq.z*v1[2]+aq.w*v1[3];
        }
      }
    }
  }
  if(PHASE==0){
    #pragma unroll
    for(int o=0;o<8;o++){
      float v = lacc[o];
      v += __shfl_xor(v,1); v += __shfl_xor(v,2); v += __shfl_xor(v,4);
      v += __shfl_xor(v,8); v += __shfl_xor(v,16);
      if(nl==0) lbuf[(size_t)(b*8+o)*784 + qg] = v;
    }
  } else {
    int c0 = o2*64 + dp;
    u16 tmp[8];
    #pragma unroll
    for(int q=0;q<8;q++) tmp[q] = f2bf(oacc[q][0]);
    *(uint4*)(attno + (size_t)(b*512+c0)*784 + q0) = *(const uint4*)tmp;
    #pragma unroll
    for(int q=0;q<8;q++) tmp[q] = f2bf(oacc[q][1]);
    *(uint4*)(attno + (size_t)(b*512+c0+32)*784 + q0) = *(const uint4*)tmp;
  }
}

// ---------------------------------------------------------------------------
extern "C" void kernel_launch(void* const* d_in, const int* in_sizes, int n_in,
                              void* d_out, int out_size, void* d_ws, size_t ws_size,
                              hipStream_t stream){
  u16* out16 = (u16*)d_out;

  if(n_in != 28){ sentinel_k<<<dim3(1),64,0,stream>>>(out16, 90112.f); return; }
  if(in_sizes[0]  != 3211264){ sentinel_k<<<dim3(1),64,0,stream>>>(out16, 88064.f); return; }
  if(in_sizes[22] != 1179648){ sentinel_k<<<dim3(1),64,0,stream>>>(out16, 81920.f); return; }
  if(out_size != 1605632){ sentinel_k<<<dim3(1),64,0,stream>>>(out16, 75776.f); return; }

  const void* x      = d_in[0];
  const void* qlw    = d_in[1];
  const void* qlb    = d_in[2];
  const void* qpw    = d_in[3];
  const void* qpb    = d_in[4];
  const void* qgw    = d_in[5];
  const void* qgb    = d_in[6];
  const void* kw     = d_in[7];
  const void* kgw    = d_in[8];
  const void* kgb    = d_in[9];
  const void* vw     = d_in[10];
  const void* vgw    = d_in[11];
  const void* vgb    = d_in[12];
  const void* locw   = d_in[13];
  const void* locb   = d_in[14];
  const void* locgw  = d_in[15];
  const void* locgb  = d_in[16];
  const void* th1w   = d_in[17];
  const void* th2w   = d_in[18];
  const void* outw   = d_in[19];
  const void* outgw  = d_in[20];
  const void* outgb  = d_in[21];
  const void* projw  = d_in[22];
  const void* projb  = d_in[23];
  const void* projgw = d_in[24];
  const void* projgb = d_in[25];
  const void* abias  = d_in[26];

  char* ws = (char*)d_ws;
  size_t off = 0;
  auto alloc = [&](size_t bytes)->void*{
    void* p = ws + off;
    off += (bytes + 255) & ~(size_t)255;
    return p;
  };
  const size_t SM_SMALL = (size_t)4*512*784*2;    // 3.21 MB
  const size_t SM_BIG   = (size_t)4*512*3136*2;   // 12.85 MB
  u16* arenaB  = (u16*)alloc(SM_BIG);             // kpre -> vpre -> opre
  u16* arenaC  = (u16*)alloc(SM_SMALL);           // projpre -> qpre -> locpre
  u16* colB    = (u16*)alloc((size_t)784*4608*2); // im2col / attno / tbufT / hbufT
  u16* arenaX  = (u16*)alloc(SM_BIG);             // xT (6.4M) -> vmap
  u16* xproj   = (u16*)alloc(SM_SMALL);
  u16* qnt     = (u16*)alloc(SM_SMALL);
  u16* knt     = (u16*)alloc(SM_BIG);
  u16* vloc    = (u16*)alloc(SM_SMALL);
  float* mbT   = (float*)alloc((size_t)3136*8*4);
  float* lbuf  = (float*)alloc((size_t)4*8*784*4);
  int*   dflag = (int*)alloc(256);
  float* st0   = (float*)alloc(4*32*2*4);
  float* st1   = (float*)alloc(4*32*2*4);
  float* st2   = (float*)alloc(4*32*2*4);
  float* st3   = (float*)alloc(4*32*2*4);
  float* st4   = (float*)alloc(4*32*2*4);
  float* st5   = (float*)alloc(4*32*2*4);

  if(off > ws_size){
    float code = 100000.f + (float)(ws_size >> 20) * 100.f;
    sentinel_k<<<dim3(1),64,0,stream>>>(out16, code);
    return;
  }

  u16* projpre = arenaC;
  u16* qpre    = arenaC;
  u16* locpre  = arenaC;
  u16* kpre    = arenaB;
  u16* vpre    = arenaB;
  u16* opre    = arenaB;
  u16* xT      = arenaX;             // consumed by k/v gemms, then overwritten:
  u16* vmap    = arenaX;             // gn_aff(vpre) -> vmap AFTER xT is dead
  u16* attno   = colB;               // colB phases: proj-col -> loc-col -> attno/hbufT
  u16* tbufT   = colB + 1806336;     // disjoint from proj-col region [0,1806336)
  u16* hbufT   = colB + 1806336;     // same slot, after tbufT is dead

  detect_k<<<dim3(1),256,0,stream>>>(x, dflag);

  // xT = transpose(x) bf16  [b][3136][256]
  transp_k<<<dim3(98,8,4),256,0,stream>>>(x, xT, dflag);

  // x_proj = GN(conv3x3s2(x, proj_w) + proj_b)   [im2col + MFMA gemm, per batch]
  for(int b=0;b<4;b++){
    im2col_bt_k<<<dim3(7056),256,0,stream>>>(x, (long)b*256*3136, colB, 256, 1, dflag);
    gemm_mfma_k<<<dim3(13,8,1),256,0,stream>>>(projw, colB, projpre + (size_t)b*512*784, projb,
        512,784,2304, 2304, 0,0,0,0, dflag);
  }
  gn_stats_k<<<dim3(32,4),256,0,stream>>>(projpre, st0, 784);
  gn_aff_k<<<dim3(784),256,0,stream>>>(projpre, st0, projgw, projgb, nullptr, xproj, 784, dflag, 0);

  // q = l2norm(GN(conv1x1(depthwise+pool) + b)) -> [q][c]
  qlocal_bt_k<<<dim3(3136),256,0,stream>>>(x, qlw, qlb, tbufT, dflag);
  gemm_mfma_k<<<dim3(13,8,4),256,0,stream>>>(qpw, tbufT, qpre, qpb,
      512,784,256, 256, 0,(long)784*256,(long)512*784,0, dflag);
  gn_stats_k<<<dim3(32,4),256,0,stream>>>(qpre, st1, 784);
  gn_l2t_k<<<dim3(49,4),256,0,stream>>>(qpre, st1, qgw, qgb, qnt, 784, dflag);

  // k = l2norm(GN(conv1x1(x))) -> [n][c]
  gemm_mfma_k<<<dim3(49,8,4),256,0,stream>>>(kw, xT, kpre, nullptr,
      512,3136,256, 256, 0,(long)3136*256,(long)512*3136,0, dflag);
  gn_stats_k<<<dim3(32,4),256,0,stream>>>(kpre, st2, 3136);
  gn_l2t_k<<<dim3(196,4),256,0,stream>>>(kpre, st2, kgw, kgb, knt, 3136, dflag);

  // v_map = GN(conv1x1(x))   [last consumer of xT; vmap then overwrites it]
  gemm_mfma_k<<<dim3(49,8,4),256,0,stream>>>(vw, xT, vpre, nullptr,
      512,3136,256, 256, 0,(long)3136*256,(long)512*3136,0, dflag);
  gn_stats_k<<<dim3(32,4),256,0,stream>>>(vpre, st3, 3136);
  gn_aff_k<<<dim3(3136),256,0,stream>>>(vpre, st3, vgw, vgb, nullptr, vmap, 3136, dflag, 0);

  // v_local = GN(groupconv3x3s2(v_map) + loc_b)  [im2col + grouped MFMA gemm]
  for(int b=0;b<4;b++){
    im2col_bt_k<<<dim3(14112),256,0,stream>>>(vmap, (long)b*512*3136, colB, 512, 0, dflag);
    gemm_mfma_k<<<dim3(13,1,8),256,0,stream>>>(locw, colB, locpre + (size_t)b*512*784, locb,
        64,784,576, 4608, (long)64*576,(long)576,(long)64*784,64, dflag);
  }
  gn_stats_k<<<dim3(32,4),256,0,stream>>>(locpre, st4, 784);
  gn_aff_k<<<dim3(784),256,0,stream>>>(locpre, st4, locgw, locgb, nullptr, vloc, 784, dflag, 0);

  // attention (two-pass, fused, clamped max-free softmax)
  mbt_k<<<dim3(98),256,0,stream>>>(th1w, abias, mbT, dflag);
  attn_k<0><<<dim3(98,1,4),256,0,stream>>>(qnt, knt, vmap, mbT, th1w, th2w, lbuf, nullptr, dflag);
  attn_k<1><<<dim3(98,1,4),256,0,stream>>>(qnt, knt, vmap, mbT, th1w, th2w, lbuf, attno, dflag);

  // out = GN(conv1x1(hardswish(attn_out + v_local))) + x_proj
  hs_addT_k<<<dim3(25,16,4),256,0,stream>>>(attno, vloc, hbufT);
  gemm_mfma_k<<<dim3(13,8,4),256,0,stream>>>(outw, hbufT, opre, nullptr,
      512,784,512, 512, 0,(long)784*512,(long)512*784,0, dflag);
  gn_stats_k<<<dim3(32,4),256,0,stream>>>(opre, st5, 784);
  gn_aff_k<<<dim3(784),256,0,stream>>>(opre, st5, outgw, outgb, xproj, d_out, 784, dflag, 1);

  sanitize_k<<<dim3(1024),256,0,stream>>>(d_out, (long)out_size, dflag);
}

// Round 11
// 1764.830 us; speedup vs baseline: 4.0407x; 1.5973x over previous
//
#include <hip/hip_runtime.h>
#include <stdint.h>

typedef unsigned short u16;
typedef unsigned int u32;
typedef __attribute__((ext_vector_type(8))) short bf16x8;
typedef __attribute__((ext_vector_type(4))) float f32x4;

#define DEV static __device__ __forceinline__

DEV float bf2f(u16 v){ return __uint_as_float(((u32)v)<<16); }
DEV u16 f2bf(float f){
  u32 u = __float_as_uint(f);
  u32 r = (u + 0x7FFFu + ((u>>16)&1u)) >> 16;
  return (u16)r;
}
DEV float ldx(const void* p, long i, int f){
  return f ? ((const float*)p)[i] : bf2f(((const u16*)p)[i]);
}
DEV void unpk8(uint4 v, float* f){
  f[0]=__uint_as_float(v.x<<16); f[1]=__uint_as_float(v.x&0xFFFF0000u);
  f[2]=__uint_as_float(v.y<<16); f[3]=__uint_as_float(v.y&0xFFFF0000u);
  f[4]=__uint_as_float(v.z<<16); f[5]=__uint_as_float(v.z&0xFFFF0000u);
  f[6]=__uint_as_float(v.w<<16); f[7]=__uint_as_float(v.w&0xFFFF0000u);
}
DEV int iabs(int a){ return a<0? -a : a; }

// ======================= dtype probe / guards =======================
__global__ void detect_k(const void* x, int* dflag){
  const u16* p = (const u16*)x;
  int t = threadIdx.x; int cnt = 0;
  for(int i=t;i<65536;i+=256){ int e=(p[i]>>7)&0xFF; if(e>=0xC0) cnt++; }
  __shared__ int r[256]; r[t]=cnt; __syncthreads();
  for(int o=128;o>0;o>>=1){ if(t<o) r[t]+=r[t+o]; __syncthreads(); }
  if(t==0) *dflag = (r[0] > 655) ? 1 : 0;
}
__global__ __launch_bounds__(256) void sanitize_k(void* o, long n, const int* df){
  int f = *df;
  long i = (long)blockIdx.x*256 + threadIdx.x;
  long st = (long)gridDim.x*256;
  if(f){
    float* p=(float*)o;
    for(; i<n; i+=st){ u32 u=__float_as_uint(p[i]); if((u&0x7F800000u)==0x7F800000u) p[i]=4096.f; }
  } else {
    u16* p=(u16*)o;
    u16 c = f2bf(4096.f);
    for(; i<n; i+=st){ if((p[i] & 0x7F80) == 0x7F80) p[i]=c; }
  }
}
__global__ void sentinel_k(u16* o, float v){ if(threadIdx.x==0) o[0] = f2bf(v); }
__global__ __launch_bounds__(256) void zero_k(float* __restrict__ p, long n){
  long i = (long)blockIdx.x*256 + threadIdx.x;
  long st = (long)gridDim.x*256;
  for(; i<n; i+=st) p[i]=0.f;
}

// ======================= data movement =======================
__global__ __launch_bounds__(256) void transp_k(const void* x, u16* __restrict__ xT, const int* df){
  __shared__ float T[32][33];
  int f = *df;
  int p0 = blockIdx.x*32, c0 = blockIdx.y*32, b = blockIdx.z;
  int tx = threadIdx.x & 31, ty = threadIdx.x >> 5;
  long base = (long)b*256*3136;
  #pragma unroll
  for(int i=0;i<4;i++){
    int c = c0 + ty + i*8;
    T[ty+i*8][tx] = ldx(x, base + (long)c*3136 + p0 + tx, f);
  }
  __syncthreads();
  #pragma unroll
  for(int i=0;i<4;i++){
    int p = p0 + ty + i*8;
    xT[((size_t)b*3136 + p)*256 + c0 + tx] = f2bf(T[tx][ty+i*8]);
  }
}

__global__ __launch_bounds__(256) void im2col_bt_k(const void* in, long off, u16* __restrict__ out,
                                                   int Cin, int isInput, const int* df){
  int f = isInput ? *df : 0;
  int K9 = Cin*9;
  int total = 784*K9;
  int id = blockIdx.x*256 + threadIdx.x;
  if(id>=total) return;
  int q = id / K9, r = id % K9;
  int ci = r/9, k = r%9;
  int oy=q/28, ox=q%28, ky=k/3, kx=k%3;
  int iy=2*oy-1+ky, ix=2*ox-1+kx;
  float v = 0.f;
  if((u32)iy<56u && (u32)ix<56u) v = ldx(in, off + (long)ci*3136 + iy*56+ix, f);
  out[id] = f2bf(v);
}

__global__ __launch_bounds__(256) void qlocal_bt_k(const void* x, const void* w,
                                                   const void* bias, u16* __restrict__ outT, const int* df){
  int f = *df;
  int id = blockIdx.x*256 + threadIdx.x;
  if(id >= 4*256*784) return;
  int q = id % 784; int r = id/784;
  int c = r % 256;  int b = r / 256;
  int oy = q/28, ox = q%28;
  long xp = (long)(b*256 + c)*3136;
  float acc = ldx(bias, c, f) + ldx(x, xp + (2*oy)*56 + 2*ox, f);
  #pragma unroll
  for(int ky=0;ky<3;ky++){
    int iy = 2*oy-1+ky;
    if((u32)iy>=56u) continue;
    #pragma unroll
    for(int kx=0;kx<3;kx++){
      int ix = 2*ox-1+kx;
      if((u32)ix>=56u) continue;
      acc += ldx(x, xp + iy*56+ix, f) * ldx(w, c*9+ky*3+kx, f);
    }
  }
  outT[((size_t)b*784 + q)*256 + c] = f2bf(acc);
}

// hardswish(obuf_fp32 + vloc) -> hbufT[b][q][c]
__global__ __launch_bounds__(256) void hs_addT_k(const float* __restrict__ a, const u16* __restrict__ bsrc,
                                                 u16* __restrict__ outT){
  __shared__ float T[32][33];
  int q0 = blockIdx.x*32, c0 = blockIdx.y*32, b = blockIdx.z;
  int tx = threadIdx.x&31, ty = threadIdx.x>>5;
  #pragma unroll
  for(int i=0;i<4;i++){
    int c = c0+ty+i*8;
    int q = q0+tx;
    float s = 0.f;
    if(q < 784){
      size_t e = ((size_t)b*512 + c)*784 + q;
      s = a[e] + bf2f(bsrc[e]);
      float cl = fminf(fmaxf(s+3.f,0.f),6.f);
      s = s*cl*(1.f/6.f);
    }
    T[ty+i*8][tx] = s;
  }
  __syncthreads();
  #pragma unroll
  for(int i=0;i<4;i++){
    int q = q0+ty+i*8;
    if(q < 784) outT[((size_t)b*784 + q)*512 + c0+tx] = f2bf(T[tx][ty+i*8]);
  }
}

// ======================= MFMA GEMM (BT convention) =======================
__global__ __launch_bounds__(256) void gemm_mfma_k(const void* A, const u16* __restrict__ BT,
                                                   u16* __restrict__ C, const void* bias,
                                                   int M, int N, int K, int ldB,
                                                   long sA, long sB, long sC, int sBias,
                                                   const int* df){
  __shared__ u16 As[64][40];
  __shared__ u16 Bs[64][40];
  int f = *df;
  int z = blockIdx.z;
  long aBase = (long)z*sA;
  const u16* Bp = BT + (size_t)z*sB;
  u16* Cp = C + (size_t)z*sC;
  int n0 = blockIdx.x*64, m0 = blockIdx.y*64;
  int t = threadIdx.x;
  int sm = t>>2, sk = (t&3)*8;
  int w = t>>6, l = t&63;
  int lm = l&15, lq = l>>4;
  f32x4 acc0={0.f,0.f,0.f,0.f}, acc1=acc0, acc2=acc0, acc3=acc0;
  bool bok = (n0 + sm) < N;
  for(int kk=0; kk<K; kk+=32){
    {
      long off = aBase + (long)(m0+sm)*K + kk + sk;
      if(f){
        const float* Af = (const float*)A;
        float4 v0 = *(const float4*)(Af+off);
        float4 v1 = *(const float4*)(Af+off+4);
        u16 tmp[8];
        tmp[0]=f2bf(v0.x); tmp[1]=f2bf(v0.y); tmp[2]=f2bf(v0.z); tmp[3]=f2bf(v0.w);
        tmp[4]=f2bf(v1.x); tmp[5]=f2bf(v1.y); tmp[6]=f2bf(v1.z); tmp[7]=f2bf(v1.w);
        *(uint4*)&As[sm][sk] = *(const uint4*)tmp;
      } else {
        *(uint4*)&As[sm][sk] = *(const uint4*)((const u16*)A + off);
      }
    }
    {
      uint4 v = {0u,0u,0u,0u};
      if(bok) v = *(const uint4*)(Bp + (size_t)(n0+sm)*ldB + kk + sk);
      *(uint4*)&Bs[sm][sk] = v;
    }
    __syncthreads();
    bf16x8 a  = *(const bf16x8*)&As[w*16 + lm][lq*8];
    bf16x8 b0 = *(const bf16x8*)&Bs[ 0 + lm][lq*8];
    bf16x8 b1 = *(const bf16x8*)&Bs[16 + lm][lq*8];
    bf16x8 b2 = *(const bf16x8*)&Bs[32 + lm][lq*8];
    bf16x8 b3 = *(const bf16x8*)&Bs[48 + lm][lq*8];
    acc0 = __builtin_amdgcn_mfma_f32_16x16x32_bf16(a, b0, acc0, 0,0,0);
    acc1 = __builtin_amdgcn_mfma_f32_16x16x32_bf16(a, b1, acc1, 0,0,0);
    acc2 = __builtin_amdgcn_mfma_f32_16x16x32_bf16(a, b2, acc2, 0,0,0);
    acc3 = __builtin_amdgcn_mfma_f32_16x16x32_bf16(a, b3, acc3, 0,0,0);
    __syncthreads();
  }
  f32x4 aa[4] = {acc0, acc1, acc2, acc3};
  int mloc = w*16 + lq*4;
  #pragma unroll
  for(int nb=0;nb<4;nb++){
    if(n0 + nb*16 >= N) break;
    int n = n0 + nb*16 + lm;
    #pragma unroll
    for(int r=0;r<4;r++){
      int m = m0 + mloc + r;
      float v = aa[nb][r];
      if(bias) v += ldx(bias, (long)z*sBias + m, f);
      Cp[(size_t)m*N + n] = f2bf(v);
    }
  }
}

// ======================= GN =======================
__global__ __launch_bounds__(256) void gn_stats_k(const u16* __restrict__ x, float* __restrict__ st, int HW){
  int g = blockIdx.x, b = blockIdx.y, t = threadIdx.x;
  size_t base = (size_t)(b*512 + g*16)*HW;
  int tot = 16*HW;
  float s=0.f, ss=0.f;
  for(int e=t; e<tot; e+=256){ float v = bf2f(x[base+e]); s+=v; ss+=v*v; }
  __shared__ float rs[256], rq[256];
  rs[t]=s; rq[t]=ss; __syncthreads();
  for(int o=128;o>0;o>>=1){ if(t<o){ rs[t]+=rs[t+o]; rq[t]+=rq[t+o]; } __syncthreads(); }
  if(t==0){
    float m = rs[0]/(float)tot;
    float var = fmaxf(rq[0]/(float)tot - m*m, 0.f);
    st[(b*32+g)*2]   = m;
    st[(b*32+g)*2+1] = rsqrtf(var + 1e-5f);
  }
}

__global__ __launch_bounds__(256) void gn_aff_k(const u16* __restrict__ x, const float* __restrict__ st,
                                                const void* w, const void* bb,
                                                const u16* __restrict__ res, void* outp, int HW,
                                                const int* df, int finalOut){
  int f = *df;
  int id = blockIdx.x*256 + threadIdx.x;
  int tot8 = 4*512*HW/8;
  if(id>=tot8) return;
  size_t e = (size_t)id*8;
  int r = (int)(e / HW);
  int c = r % 512; int b = r / 512;
  int g = c>>4;
  float mean = st[(b*32+g)*2], rstd = st[(b*32+g)*2+1];
  float sw = ldx(w,c,f)*rstd;
  float sb = ldx(bb,c,f) - mean*sw;
  uint4 rv = *(const uint4*)(x + e);
  float fv[8]; unpk8(rv, fv);
  float o[8];
  #pragma unroll
  for(int j=0;j<8;j++) o[j] = fv[j]*sw + sb;
  if(res){
    uint4 rr = *(const uint4*)(res + e);
    float fr[8]; unpk8(rr, fr);
    #pragma unroll
    for(int j=0;j<8;j++) o[j] += fr[j];
  }
  if(finalOut && f){
    float* o32 = (float*)outp;
    #pragma unroll
    for(int j=0;j<8;j++) o32[e+j] = o[j];
  } else {
    u16 tmp[8];
    #pragma unroll
    for(int j=0;j<8;j++) tmp[j] = f2bf(o[j]);
    *(uint4*)((u16*)outp + e) = *(const uint4*)tmp;
  }
}

__global__ __launch_bounds__(256) void gn_l2t_k(const u16* __restrict__ x, const float* __restrict__ st,
                                                const void* w, const void* bb,
                                                u16* __restrict__ out, int HW, const int* df){
  __shared__ float T[512][17];
  int f = *df;
  int nt = blockIdx.x, b = blockIdx.y, t = threadIdx.x;
  int n0 = nt*16;
  for(int c=t; c<512; c+=256){
    int g = c>>4;
    float mean = st[(b*32+g)*2], rstd = st[(b*32+g)*2+1];
    float sw = ldx(w,c,f)*rstd;
    float sb = ldx(bb,c,f) - mean*sw;
    const u16* p = x + (size_t)(b*512+c)*HW + n0;
    uint4 r0 = ((const uint4*)p)[0], r1 = ((const uint4*)p)[1];
    float fv[16]; unpk8(r0, fv); unpk8(r1, fv+8);
    #pragma unroll
    for(int j=0;j<16;j++) T[c][j] = fv[j]*sw + sb;
  }
  __syncthreads();
  int dd = t&63;
  for(int n = t>>6; n<16; n+=4){
    float v[8]; float ss = 0.f;
    #pragma unroll
    for(int h=0;h<8;h++){ v[h] = T[h*64+dd][n]; ss += v[h]*v[h]; }
    float rn = 1.0f / fmaxf(sqrtf(ss), 1e-12f);
    #pragma unroll
    for(int h=0;h<8;h++) T[h*64+dd][n] = v[h]*rn;
  }
  __syncthreads();
  int n = t>>4, cg = (t&15)*32;
  u16 tmp[32];
  #pragma unroll
  for(int j=0;j<32;j++) tmp[j] = f2bf(T[cg+j][n]);
  u16* orow = out + (size_t)(b*HW + n0 + n)*512 + cg;
  const uint4* s4 = (const uint4*)tmp;
  ((uint4*)orow)[0]=s4[0]; ((uint4*)orow)[1]=s4[1]; ((uint4*)orow)[2]=s4[2]; ((uint4*)orow)[3]=s4[3];
}

__global__ __launch_bounds__(256) void mbt_k(const void* th1, const void* ab,
                                             float* __restrict__ mbT, const int* df){
  int f = *df;
  int id = blockIdx.x*256 + threadIdx.x;
  if(id >= 3136*8) return;
  int o = id & 7; int idx = id >> 3;
  float s = 0.f;
  #pragma unroll
  for(int i=0;i<8;i++) s += ldx(th1, o*8+i, f) * ldx(ab, (long)i*3136+idx, f);
  mbT[id] = s;
}

// ======================= MFMA attention =======================
// One wave per (b, 16-q tile, n-split slice). QK per head via 16x16x32 MFMA
// (K frags direct from knt global), th1/exp/th2 per-lane in registers
// (dt[i] C-layout: lane holds 4 (q,n) pairs x 8 heads), PV via MFMA with
// V frags direct from vmap (already B-operand layout). Two-pass max-free
// softmax: phase0 -> lbuf (atomic over n-splits), phase1 -> obuf fp32.
template<int PHASE>
__global__ __launch_bounds__(64) void attn_mfma_k(const u16* __restrict__ qnt,
    const u16* __restrict__ knt, const u16* __restrict__ vmap,
    const float* __restrict__ mbT, const void* th1w, const void* th2w,
    const float* __restrict__ lin, float* __restrict__ lout,
    float* __restrict__ obuf, const int* df){
  __shared__ u16 Qs[16*520];      // 16 q rows x 512 ch (pad 520: 2-way free)
  __shared__ u16 A2s[8*16*40];    // 8 oo x 16 q x 32 n (pad 40)
  __shared__ float TH[128];
  __shared__ float LINV[128];
  int f = *df;
  int b = blockIdx.z;
  int q0 = blockIdx.x*16;
  int c0 = blockIdx.y*25, c1 = min(98, c0+25);
  int t = threadIdx.x, lm = t&15, lq = t>>4;
  for(int i=t;i<128;i+=64) TH[i] = (i<64)? ldx(th1w,i,f) : ldx(th2w,i-64,f);
  for(int i=t;i<1024;i+=64){
    int row=i>>6, col=(i&63)*8;
    *(uint4*)&Qs[row*520+col] = *(const uint4*)(qnt + ((size_t)b*784+q0+row)*512 + col);
  }
  if(PHASE==1){
    for(int i=t;i<128;i+=64){
      float lv = lin[((size_t)b*8+(i>>4))*784 + q0 + (i&15)];
      LINV[i] = (lv>0.f)? 1.0f/lv : 0.f;
    }
  }
  __syncthreads();
  int qy2[4], qx2[4];
  #pragma unroll
  for(int r=0;r<4;r++){ int qg=q0+lq*4+r; qy2[r]=2*(qg/28); qx2[r]=2*(qg%28); }
  f32x4 outa[32];
  float lacc[8][4];
  if(PHASE==1){
    #pragma unroll
    for(int i=0;i<32;i++) outa[i] = (f32x4){0.f,0.f,0.f,0.f};
  } else {
    #pragma unroll
    for(int o=0;o<8;o++)
      #pragma unroll
      for(int r=0;r<4;r++) lacc[o][r]=0.f;
  }

  for(int ch=c0; ch<c1; ch++){
    int n0 = ch*32;
    __syncthreads();   // A2s WAR guard across chunks
    #pragma unroll
    for(int st=0; st<2; st++){
      int ng = n0 + st*16 + lm;
      const u16* krow = knt + ((size_t)b*3136 + ng)*512;
      f32x4 dt[8];
      #pragma unroll
      for(int i=0;i<8;i++){
        bf16x8 qa0 = *(const bf16x8*)&Qs[lm*520 + i*64 + lq*8];
        bf16x8 qa1 = *(const bf16x8*)&Qs[lm*520 + i*64 + 32 + lq*8];
        bf16x8 kb0 = *(const bf16x8*)(krow + i*64 + lq*8);
        bf16x8 kb1 = *(const bf16x8*)(krow + i*64 + 32 + lq*8);
        f32x4 z = {0.f,0.f,0.f,0.f};
        z = __builtin_amdgcn_mfma_f32_16x16x32_bf16(qa0, kb0, z, 0,0,0);
        dt[i] = __builtin_amdgcn_mfma_f32_16x16x32_bf16(qa1, kb1, z, 0,0,0);
      }
      int ny = ng/56, nx = ng%56;
      #pragma unroll
      for(int r=0;r<4;r++){
        int idx = iabs(qy2[r]-ny)*56 + iabs(qx2[r]-nx);
        const float* mb = &mbT[idx*8];
        float p8[8];
        #pragma unroll
        for(int o=0;o<8;o++){
          float s = 0.f;
          #pragma unroll
          for(int i=0;i<8;i++) s += TH[o*8+i]*dt[i][r];
          p8[o] = __expf(fminf(s*0.125f + mb[o], 60.f));
        }
        if(PHASE==0){
          #pragma unroll
          for(int o=0;o<8;o++) lacc[o][r] += p8[o];
        } else {
          #pragma unroll
          for(int o=0;o<8;o++) p8[o] *= LINV[o*16 + lq*4 + r];
          #pragma unroll
          for(int oo=0;oo<8;oo++){
            float s = 0.f;
            #pragma unroll
            for(int o=0;o<8;o++) s += TH[64+oo*8+o]*p8[o];
            A2s[(oo*16 + lq*4 + r)*40 + st*16 + lm] = f2bf(s);
          }
        }
      }
    }
    if(PHASE==1){
      __syncthreads();
      #pragma unroll
      for(int oo=0;oo<8;oo++){
        bf16x8 a2f = *(const bf16x8*)&A2s[(oo*16 + lm)*40 + lq*8];
        #pragma unroll
        for(int j=0;j<4;j++){
          int c = (oo*4+j)*16 + lm;
          bf16x8 vb = *(const bf16x8*)(vmap + ((size_t)b*512 + c)*3136 + n0 + lq*8);
          outa[oo*4+j] = __builtin_amdgcn_mfma_f32_16x16x32_bf16(a2f, vb, outa[oo*4+j], 0,0,0);
        }
      }
    }
  }
  if(PHASE==0){
    #pragma unroll
    for(int o=0;o<8;o++)
      #pragma unroll
      for(int r=0;r<4;r++){
        float v = lacc[o][r];
        v += __shfl_xor(v,1); v += __shfl_xor(v,2);
        v += __shfl_xor(v,4); v += __shfl_xor(v,8);
        if(lm==0) atomicAdd(&lout[((size_t)b*8+o)*784 + q0 + lq*4 + r], v);
      }
  } else {
    #pragma unroll
    for(int ct=0;ct<32;ct++){
      int c = ct*16 + lm;
      float* op = obuf + ((size_t)b*512+c)*784 + q0 + lq*4;
      atomicAdd(op+0, outa[ct][0]);
      atomicAdd(op+1, outa[ct][1]);
      atomicAdd(op+2, outa[ct][2]);
      atomicAdd(op+3, outa[ct][3]);
    }
  }
}

// ---------------------------------------------------------------------------
extern "C" void kernel_launch(void* const* d_in, const int* in_sizes, int n_in,
                              void* d_out, int out_size, void* d_ws, size_t ws_size,
                              hipStream_t stream){
  u16* out16 = (u16*)d_out;

  if(n_in != 28){ sentinel_k<<<dim3(1),64,0,stream>>>(out16, 90112.f); return; }
  if(in_sizes[0]  != 3211264){ sentinel_k<<<dim3(1),64,0,stream>>>(out16, 88064.f); return; }
  if(in_sizes[22] != 1179648){ sentinel_k<<<dim3(1),64,0,stream>>>(out16, 81920.f); return; }
  if(out_size != 1605632){ sentinel_k<<<dim3(1),64,0,stream>>>(out16, 75776.f); return; }

  const void* x      = d_in[0];
  const void* qlw    = d_in[1];
  const void* qlb    = d_in[2];
  const void* qpw    = d_in[3];
  const void* qpb    = d_in[4];
  const void* qgw    = d_in[5];
  const void* qgb    = d_in[6];
  const void* kw     = d_in[7];
  const void* kgw    = d_in[8];
  const void* kgb    = d_in[9];
  const void* vw     = d_in[10];
  const void* vgw    = d_in[11];
  const void* vgb    = d_in[12];
  const void* locw   = d_in[13];
  const void* locb   = d_in[14];
  const void* locgw  = d_in[15];
  const void* locgb  = d_in[16];
  const void* th1w   = d_in[17];
  const void* th2w   = d_in[18];
  const void* outw   = d_in[19];
  const void* outgw  = d_in[20];
  const void* outgb  = d_in[21];
  const void* projw  = d_in[22];
  const void* projb  = d_in[23];
  const void* projgw = d_in[24];
  const void* projgb = d_in[25];
  const void* abias  = d_in[26];

  char* ws = (char*)d_ws;
  size_t off = 0;
  auto alloc = [&](size_t bytes)->void*{
    void* p = ws + off;
    off += (bytes + 255) & ~(size_t)255;
    return p;
  };
  const size_t SM_SMALL = (size_t)4*512*784*2;    // 3.21 MB
  const size_t SM_BIG   = (size_t)4*512*3136*2;   // 12.85 MB
  u16* arenaB  = (u16*)alloc(SM_BIG);             // kpre -> vpre -> opre
  u16* arenaC  = (u16*)alloc(SM_SMALL);           // projpre -> qpre -> locpre -> hbufT
  u16* colB    = (u16*)alloc((size_t)784*4608*2); // im2col -> obuf(fp32) / tbufT
  u16* arenaX  = (u16*)alloc(SM_BIG);             // xT -> vmap
  u16* xproj   = (u16*)alloc(SM_SMALL);
  u16* qnt     = (u16*)alloc(SM_SMALL);
  u16* knt     = (u16*)alloc(SM_BIG);
  u16* vloc    = (u16*)alloc(SM_SMALL);
  float* mbT   = (float*)alloc((size_t)3136*8*4);
  float* lbuf  = (float*)alloc((size_t)4*8*784*4);
  int*   dflag = (int*)alloc(256);
  float* st0   = (float*)alloc(4*32*2*4);
  float* st1   = (float*)alloc(4*32*2*4);
  float* st2   = (float*)alloc(4*32*2*4);
  float* st3   = (float*)alloc(4*32*2*4);
  float* st4   = (float*)alloc(4*32*2*4);
  float* st5   = (float*)alloc(4*32*2*4);

  if(off > ws_size){
    float code = 100000.f + (float)(ws_size >> 20) * 100.f;
    sentinel_k<<<dim3(1),64,0,stream>>>(out16, code);
    return;
  }

  u16* projpre = arenaC;
  u16* qpre    = arenaC;
  u16* locpre  = arenaC;
  u16* hbufT   = arenaC;             // after locpre/vloc done
  u16* kpre    = arenaB;
  u16* vpre    = arenaB;
  u16* opre    = arenaB;
  u16* xT      = arenaX;
  u16* vmap    = arenaX;             // after xT dead
  u16* tbufT   = colB + 1806336;     // disjoint from proj-col region
  float* obuf  = (float*)colB;       // 6.42 MB fp32, after loc im2col done

  detect_k<<<dim3(1),256,0,stream>>>(x, dflag);

  // xT = transpose(x) bf16
  transp_k<<<dim3(98,8,4),256,0,stream>>>(x, xT, dflag);

  // x_proj = GN(conv3x3s2(x, proj_w) + proj_b)
  for(int b=0;b<4;b++){
    im2col_bt_k<<<dim3(7056),256,0,stream>>>(x, (long)b*256*3136, colB, 256, 1, dflag);
    gemm_mfma_k<<<dim3(13,8,1),256,0,stream>>>(projw, colB, projpre + (size_t)b*512*784, projb,
        512,784,2304, 2304, 0,0,0,0, dflag);
  }
  gn_stats_k<<<dim3(32,4),256,0,stream>>>(projpre, st0, 784);
  gn_aff_k<<<dim3(784),256,0,stream>>>(projpre, st0, projgw, projgb, nullptr, xproj, 784, dflag, 0);

  // q = l2norm(GN(conv1x1(depthwise+pool) + b)) -> [q][c]
  qlocal_bt_k<<<dim3(3136),256,0,stream>>>(x, qlw, qlb, tbufT, dflag);
  gemm_mfma_k<<<dim3(13,8,4),256,0,stream>>>(qpw, tbufT, qpre, qpb,
      512,784,256, 256, 0,(long)784*256,(long)512*784,0, dflag);
  gn_stats_k<<<dim3(32,4),256,0,stream>>>(qpre, st1, 784);
  gn_l2t_k<<<dim3(49,4),256,0,stream>>>(qpre, st1, qgw, qgb, qnt, 784, dflag);

  // k = l2norm(GN(conv1x1(x))) -> [n][c]
  gemm_mfma_k<<<dim3(49,8,4),256,0,stream>>>(kw, xT, kpre, nullptr,
      512,3136,256, 256, 0,(long)3136*256,(long)512*3136,0, dflag);
  gn_stats_k<<<dim3(32,4),256,0,stream>>>(kpre, st2, 3136);
  gn_l2t_k<<<dim3(196,4),256,0,stream>>>(kpre, st2, kgw, kgb, knt, 3136, dflag);

  // v_map = GN(conv1x1(x))
  gemm_mfma_k<<<dim3(49,8,4),256,0,stream>>>(vw, xT, vpre, nullptr,
      512,3136,256, 256, 0,(long)3136*256,(long)512*3136,0, dflag);
  gn_stats_k<<<dim3(32,4),256,0,stream>>>(vpre, st3, 3136);
  gn_aff_k<<<dim3(3136),256,0,stream>>>(vpre, st3, vgw, vgb, nullptr, vmap, 3136, dflag, 0);

  // v_local = GN(groupconv3x3s2(v_map) + loc_b)
  for(int b=0;b<4;b++){
    im2col_bt_k<<<dim3(14112),256,0,stream>>>(vmap, (long)b*512*3136, colB, 512, 0, dflag);
    gemm_mfma_k<<<dim3(13,1,8),256,0,stream>>>(locw, colB, locpre + (size_t)b*512*784, locb,
        64,784,576, 4608, (long)64*576,(long)576,(long)64*784,64, dflag);
  }
  gn_stats_k<<<dim3(32,4),256,0,stream>>>(locpre, st4, 784);
  gn_aff_k<<<dim3(784),256,0,stream>>>(locpre, st4, locgw, locgb, nullptr, vloc, 784, dflag, 0);

  // attention: MFMA QK/PV, two-pass max-free softmax
  mbt_k<<<dim3(98),256,0,stream>>>(th1w, abias, mbT, dflag);
  zero_k<<<dim3(32),256,0,stream>>>(lbuf, 4L*8*784);
  zero_k<<<dim3(1024),256,0,stream>>>(obuf, 4L*512*784);
  attn_mfma_k<0><<<dim3(49,4,4),64,0,stream>>>(qnt, knt, vmap, mbT, th1w, th2w,
      nullptr, lbuf, nullptr, dflag);
  attn_mfma_k<1><<<dim3(49,4,4),64,0,stream>>>(qnt, knt, vmap, mbT, th1w, th2w,
      lbuf, nullptr, obuf, dflag);

  // out = GN(conv1x1(hardswish(attn_out + v_local))) + x_proj
  hs_addT_k<<<dim3(25,16,4),256,0,stream>>>(obuf, vloc, hbufT);
  gemm_mfma_k<<<dim3(13,8,4),256,0,stream>>>(outw, hbufT, opre, nullptr,
      512,784,512, 512, 0,(long)784*512,(long)512*784,0, dflag);
  gn_stats_k<<<dim3(32,4),256,0,stream>>>(opre, st5, 784);
  gn_aff_k<<<dim3(784),256,0,stream>>>(opre, st5, outgw, outgb, xproj, d_out, 784, dflag, 1);

  sanitize_k<<<dim3(1024),256,0,stream>>>(d_out, (long)out_size, dflag);
}